// Round 1
// baseline (601.775 us; speedup 1.0000x reference)
//
#include <hip/hip_runtime.h>

typedef unsigned short u16;
typedef unsigned int   u32;
typedef __bf16  bf16x8 __attribute__((ext_vector_type(8)));
typedef float   f32x4  __attribute__((ext_vector_type(4)));
typedef u16     u16x4  __attribute__((ext_vector_type(4)));
typedef u16     u16x8  __attribute__((ext_vector_type(8)));

#define S_LEN 2048
#define HID 2048
#define NH 32
#define NKVH 8
#define HD 128
#define QSTRIDE 4096   /* NH*HD   */
#define KSTRIDE 1024   /* NKVH*HD */
#define ATT_SCALE 0.08838834764831845f

__device__ __forceinline__ u16 f2bf(float f){
  u32 u = __builtin_bit_cast(u32, f);
  u += 0x7FFFu + ((u >> 16) & 1u);
  return (u16)(u >> 16);
}
__device__ __forceinline__ float bf2f(u16 h){
  u32 u = ((u32)h) << 16;
  return __builtin_bit_cast(float, u);
}

// ---------------- f32 -> bf16 convert (vectorized) ----------------
__global__ void cvt_kernel(const f32x4* __restrict__ in, u16x4* __restrict__ out, int n4){
  int i = blockIdx.x * 256 + threadIdx.x;
  if (i >= n4) return;
  f32x4 v = in[i];
  u16x4 o;
  o[0] = f2bf(v[0]); o[1] = f2bf(v[1]); o[2] = f2bf(v[2]); o[3] = f2bf(v[3]);
  out[i] = o;
}

// ---------------- GEMM: C[M][N] = X[M][K] @ W[N][K]^T (bf16 in, f32 acc) ----
// 128x128 block tile, BK=32, 4 waves (2x2), each wave 64x64 = 4x4 mfma frags.
// Reg-staged LDS (no global_load_lds this round - compile-risk-free baseline).
template<int OUT_BF16>
__global__ __launch_bounds__(256, 2)
void gemm_bt_kernel(const u16* __restrict__ X, const u16* __restrict__ W,
                    void* __restrict__ Cv, int M, int N, int K){
  __shared__ __align__(16) u16 As[128 * 32];
  __shared__ __align__(16) u16 Bs[128 * 32];
  const int m0 = blockIdx.y * 128, n0 = blockIdx.x * 128;
  const int tid = threadIdx.x;
  const int wave = tid >> 6, lane = tid & 63;
  const int wm = wave >> 1, wn = wave & 1;
  const int g = lane >> 4, ln = lane & 15;
  // staging assignment: 512 16B-chunks per tile; thread covers chunk tid and tid+256
  const int r0 = tid >> 2;            // rows 0..63
  const int r1 = r0 + 64;             // rows 64..127
  const int cc = (tid & 3) * 8;       // bf16 element column within BK=32
  f32x4 acc[4][4] = {};
  const u16* xa0 = X + (size_t)(m0 + r0) * K + cc;
  const u16* xa1 = X + (size_t)(m0 + r1) * K + cc;
  const u16* wb0 = W + (size_t)(n0 + r0) * K + cc;
  const u16* wb1 = W + (size_t)(n0 + r1) * K + cc;

  for (int k0 = 0; k0 < K; k0 += 32){
    u16x8 a0 = *(const u16x8*)(xa0 + k0);
    u16x8 a1 = *(const u16x8*)(xa1 + k0);
    u16x8 b0 = *(const u16x8*)(wb0 + k0);
    u16x8 b1 = *(const u16x8*)(wb1 + k0);
    __syncthreads();                       // prior tile fully consumed
    *(u16x8*)&As[r0 * 32 + cc] = a0;
    *(u16x8*)&As[r1 * 32 + cc] = a1;
    *(u16x8*)&Bs[r0 * 32 + cc] = b0;
    *(u16x8*)&Bs[r1 * 32 + cc] = b1;
    __syncthreads();
    bf16x8 a[4], b[4];
    #pragma unroll
    for (int f = 0; f < 4; f++) a[f] = *(const bf16x8*)&As[(wm * 64 + f * 16 + ln) * 32 + g * 8];
    #pragma unroll
    for (int f = 0; f < 4; f++) b[f] = *(const bf16x8*)&Bs[(wn * 64 + f * 16 + ln) * 32 + g * 8];
    #pragma unroll
    for (int i = 0; i < 4; i++)
      #pragma unroll
      for (int j = 0; j < 4; j++)
        acc[i][j] = __builtin_amdgcn_mfma_f32_16x16x32_bf16(a[i], b[j], acc[i][j], 0, 0, 0);
  }
  // epilogue: C/D layout col = lane&15, row = (lane>>4)*4 + reg  [m89-verified]
  #pragma unroll
  for (int i = 0; i < 4; i++)
    #pragma unroll
    for (int j = 0; j < 4; j++)
      #pragma unroll
      for (int r = 0; r < 4; r++){
        int row = m0 + wm * 64 + i * 16 + g * 4 + r;
        int col = n0 + wn * 64 + j * 16 + ln;
        if (OUT_BF16) ((u16*)Cv)[(size_t)row * N + col] = f2bf(acc[i][j][r]);
        else          ((float*)Cv)[(size_t)row * N + col] = acc[i][j][r];
      }
}

// ---------------- partial RoPE (R=64), in place on bf16 Q/K ----------------
// head < 32 -> Q [s][h*128+d] (stride 4096); else K head-32 [s][kvh*128+d] (stride 1024)
__global__ void rope_kernel(u16* __restrict__ QP, u16* __restrict__ KP,
                            const float* __restrict__ cosv, const float* __restrict__ sinv){
  int idx = blockIdx.x * 256 + threadIdx.x;
  if (idx >= S_LEN * (NH + NKVH) * 32) return;
  int dp   = idx & 31;
  int head = (idx >> 5) % (NH + NKVH);
  int s    = idx / ((NH + NKVH) * 32);
  u16* p = (head < NH) ? (QP + (size_t)s * QSTRIDE + head * HD)
                       : (KP + (size_t)s * KSTRIDE + (head - NH) * HD);
  float c  = cosv[s * 64 + dp];
  float sn = sinv[s * 64 + dp];  // cos/sin repeat: [dp] == [dp+32]
  float x0 = bf2f(p[dp]);
  float x1 = bf2f(p[dp + 32]);
  p[dp]      = f2bf(x0 * c - x1 * sn);
  p[dp + 32] = f2bf(x1 * c + x0 * sn);
}

// ---------------- V transpose: VT[kvh][vd][s] = VP[s][kvh*128+vd] ----------
__global__ void vtrans_kernel(const u16* __restrict__ VP, u16* __restrict__ VT){
  int idx = blockIdx.x * 256 + threadIdx.x;
  if (idx >= NKVH * HD * S_LEN) return;
  int s   = idx & (S_LEN - 1);
  int vd  = (idx >> 11) & (HD - 1);
  int kvh = idx >> 18;
  VT[idx] = VP[(size_t)s * KSTRIDE + kvh * HD + vd];
}

// ---------------- causal flash attention with sink, GQA 4:1 ----------------
// 1 wave per block; block = (q-tile of 16 rows, head). Online softmax.
__global__ __launch_bounds__(64)
void attn_kernel(const u16* __restrict__ Q, const u16* __restrict__ Kc,
                 const u16* __restrict__ VT, const float* __restrict__ sinkb,
                 u16* __restrict__ AO){
  const int qt = blockIdx.x, h = blockIdx.y;
  const int lane = threadIdx.x;
  const int g = lane >> 4, ln = lane & 15;
  const int kvh = h >> 2;           // jnp.repeat: head h -> kv head h/4
  const int q0 = qt * 16;
  __shared__ __align__(16) u16 Ps[16 * 32];

  // Q fragments: A[m][k], m = lane%16 (q-row), k = 8*(lane/16)+j
  bf16x8 qf[4];
  const u16* qrow = Q + (size_t)(q0 + ln) * QSTRIDE + h * HD;
  #pragma unroll
  for (int t = 0; t < 4; t++) qf[t] = *(const bf16x8*)(qrow + t * 32 + g * 8);

  f32x4 O[8] = {};
  float m_r[4], l_r[4];
  #pragma unroll
  for (int r = 0; r < 4; r++){ m_r[r] = -3.0e38f; l_r[r] = 0.f; }

  const int nkt = (q0 + 15) / 32 + 1;
  for (int kt = 0; kt < nkt; kt++){
    const int k0 = kt * 32;
    f32x4 sc0 = {}, sc1 = {};
    const u16* kbase = Kc + (size_t)(k0 + ln) * KSTRIDE + kvh * HD;
    #pragma unroll
    for (int t = 0; t < 4; t++){
      bf16x8 kf0 = *(const bf16x8*)(kbase + t * 32 + g * 8);
      bf16x8 kf1 = *(const bf16x8*)(kbase + (size_t)16 * KSTRIDE + t * 32 + g * 8);
      sc0 = __builtin_amdgcn_mfma_f32_16x16x32_bf16(qf[t], kf0, sc0, 0, 0, 0);
      sc1 = __builtin_amdgcn_mfma_f32_16x16x32_bf16(qf[t], kf1, sc1, 0, 0, 0);
    }
    // scores: row (q) = g*4+r, col (key) = k0 + frag*16 + ln
    const bool needmask = (k0 + 31 > q0);
    float lg[2][4];
    #pragma unroll
    for (int r = 0; r < 4; r++){
      int qg = q0 + g * 4 + r;
      float v0 = sc0[r] * ATT_SCALE;
      float v1 = sc1[r] * ATT_SCALE;
      if (needmask){
        if (k0 + ln      > qg) v0 = -1e30f;
        if (k0 + 16 + ln > qg) v1 = -1e30f;
      }
      lg[0][r] = v0; lg[1][r] = v1;
    }
    float mn[4], sf[4];
    #pragma unroll
    for (int r = 0; r < 4; r++){
      float t = fmaxf(lg[0][r], lg[1][r]);
      #pragma unroll
      for (int d = 1; d < 16; d <<= 1) t = fmaxf(t, __shfl_xor(t, d));
      mn[r] = fmaxf(m_r[r], t);
      sf[r] = __expf(m_r[r] - mn[r]);
      m_r[r] = mn[r];
    }
    #pragma unroll
    for (int r = 0; r < 4; r++){
      float p0 = __expf(lg[0][r] - mn[r]);
      float p1 = __expf(lg[1][r] - mn[r]);
      float rsum = p0 + p1;
      #pragma unroll
      for (int d = 1; d < 16; d <<= 1) rsum += __shfl_xor(rsum, d);
      l_r[r] = l_r[r] * sf[r] + rsum;
      Ps[(g * 4 + r) * 32 + ln]      = f2bf(p0);
      Ps[(g * 4 + r) * 32 + 16 + ln] = f2bf(p1);
    }
    #pragma unroll
    for (int fn = 0; fn < 8; fn++)
      #pragma unroll
      for (int r = 0; r < 4; r++) O[fn][r] *= sf[r];
    __syncthreads();
    // P A-frag: row = ln, k = g*8+j ; V B-frag from VT contiguous along s
    bf16x8 pa = *(const bf16x8*)&Ps[ln * 32 + g * 8];
    const u16* vbase = VT + (size_t)kvh * HD * S_LEN + k0 + g * 8;
    #pragma unroll
    for (int fn = 0; fn < 8; fn++){
      bf16x8 vf = *(const bf16x8*)(vbase + (size_t)(fn * 16 + ln) * S_LEN);
      O[fn] = __builtin_amdgcn_mfma_f32_16x16x32_bf16(pa, vf, O[fn], 0, 0, 0);
    }
    __syncthreads();
  }
  // fold in sink: denominator gets exp(sink - m_tot); numerator rescaled
  float sb = sinkb[h];
  #pragma unroll
  for (int r = 0; r < 4; r++){
    float mt = fmaxf(m_r[r], sb);
    float lt = l_r[r] * __expf(m_r[r] - mt) + __expf(sb - mt);
    float osc = __expf(m_r[r] - mt) / lt;
    #pragma unroll
    for (int fn = 0; fn < 8; fn++){
      AO[(size_t)(q0 + g * 4 + r) * QSTRIDE + h * HD + fn * 16 + ln] = f2bf(O[fn][r] * osc);
    }
  }
}

// ---------------- host-side launch ----------------
extern "C" void kernel_launch(void* const* d_in, const int* in_sizes, int n_in,
                              void* d_out, int out_size, void* d_ws, size_t ws_size,
                              hipStream_t stream){
  (void)in_sizes; (void)n_in; (void)out_size; (void)ws_size;
  const float* hs    = (const float*)d_in[0];
  const float* cosv  = (const float*)d_in[1];
  const float* sinv  = (const float*)d_in[2];
  /* d_in[3] attention_mask: pure causal triu(NEG,1) - implemented directly */
  const float* Wq    = (const float*)d_in[4];
  const float* Wk    = (const float*)d_in[5];
  const float* Wv    = (const float*)d_in[6];
  const float* Wo    = (const float*)d_in[7];
  const float* sinkb = (const float*)d_in[8];
  float* out = (float*)d_out;

  char* ws = (char*)d_ws;
  u16* XB  = (u16*)(ws);                    //  8,388,608  X bf16 [2048][2048]
  u16* WQB = (u16*)(ws + 8388608);          // 16,777,216  Wq bf16 [4096][2048]
  u16* WKB = (u16*)(ws + 25165824);         //  4,194,304  Wk bf16 [1024][2048]
  u16* WVB = (u16*)(ws + 29360128);         //  4,194,304  Wv bf16 [1024][2048]
  u16* WOB = (u16*)(ws + 33554432);         // 16,777,216  Wo bf16 [2048][4096]
  u16* QP  = (u16*)(ws + 50331648);         // 16,777,216  Q  bf16 [2048][4096]
  u16* KP  = (u16*)(ws + 67108864);         //  4,194,304  K  bf16 [2048][1024]
  u16* VP  = (u16*)(ws + 71303168);         //  4,194,304  V  bf16 [2048][1024]
  u16* VT  = (u16*)(ws + 75497472);         //  4,194,304  V^T bf16 [8][128][2048]
  u16* AO  = (u16*)(ws + 79691776);         // 16,777,216  attn out bf16 [2048][4096]

  // converts
  cvt_kernel<<<4096, 256, 0, stream>>>((const f32x4*)hs, (u16x4*)XB, 1048576);
  cvt_kernel<<<8192, 256, 0, stream>>>((const f32x4*)Wq, (u16x4*)WQB, 2097152);
  cvt_kernel<<<2048, 256, 0, stream>>>((const f32x4*)Wk, (u16x4*)WKB, 524288);
  cvt_kernel<<<2048, 256, 0, stream>>>((const f32x4*)Wv, (u16x4*)WVB, 524288);
  cvt_kernel<<<8192, 256, 0, stream>>>((const f32x4*)Wo, (u16x4*)WOB, 2097152);

  // QKV projections
  gemm_bt_kernel<1><<<dim3(32, 16), 256, 0, stream>>>(XB, WQB, QP, 2048, 4096, 2048);
  gemm_bt_kernel<1><<<dim3(8, 16),  256, 0, stream>>>(XB, WKB, KP, 2048, 1024, 2048);
  gemm_bt_kernel<1><<<dim3(8, 16),  256, 0, stream>>>(XB, WVB, VP, 2048, 1024, 2048);

  // RoPE (in place) + V transpose
  rope_kernel<<<10240, 256, 0, stream>>>(QP, KP, cosv, sinv);
  vtrans_kernel<<<8192, 256, 0, stream>>>(VP, VT);

  // attention
  attn_kernel<<<dim3(128, 32), 64, 0, stream>>>(QP, KP, VT, sinkb, AO);

  // output projection (f32 out)
  gemm_bt_kernel<0><<<dim3(16, 16), 256, 0, stream>>>(AO, WOB, out, 2048, 2048, 4096);
}

// Round 2
// 422.036 us; speedup vs baseline: 1.4259x; 1.4259x over previous
//
#include <hip/hip_runtime.h>

typedef unsigned short u16;
typedef unsigned int   u32;
typedef __bf16  bf16x8 __attribute__((ext_vector_type(8)));
typedef float   f32x4  __attribute__((ext_vector_type(4)));
typedef u16     u16x4  __attribute__((ext_vector_type(4)));
typedef u16     u16x8  __attribute__((ext_vector_type(8)));

#define S_LEN 2048
#define NH 32
#define NKVH 8
#define HD 128
#define QKVST 6144          /* packed QKV row stride  */
#define AOST  4096          /* attn-out row stride    */
#define ATT_SCALE 0.08838834764831845f

__device__ __forceinline__ u16 f2bf(float f){
  u32 u = __builtin_bit_cast(u32, f);
  u += 0x7FFFu + ((u >> 16) & 1u);
  return (u16)(u >> 16);
}
__device__ __forceinline__ float bf2f(u16 h){
  u32 u = ((u32)h) << 16;
  return __builtin_bit_cast(float, u);
}
// async global->LDS, 16B per lane. Dest must be wave-uniform base + lane*16.
__device__ __forceinline__ void gload_lds16(const u16* g, u16* l){
  __builtin_amdgcn_global_load_lds(
      (const __attribute__((address_space(1))) void*)g,
      (__attribute__((address_space(3))) void*)l, 16, 0, 0);
}

// ---------------- f32 -> bf16 convert (vectorized) ----------------
__global__ void cvt_kernel(const f32x4* __restrict__ in, u16x4* __restrict__ out, int n4){
  int i = blockIdx.x * 256 + threadIdx.x;
  if (i >= n4) return;
  f32x4 v = in[i];
  u16x4 o;
  o[0] = f2bf(v[0]); o[1] = f2bf(v[1]); o[2] = f2bf(v[2]); o[3] = f2bf(v[3]);
  out[i] = o;
}

// ---------------- GEMM: C[M][N] = X[M][K] @ W[N][K]^T (bf16 in, f32 acc) ----
// 128x128 tile, BK=32, 4 waves (2x2), global_load_lds width-16 staging (m97).
template<int OUT_BF16>
__global__ __launch_bounds__(256, 2)
void gemm_bt_kernel(const u16* __restrict__ X, const u16* __restrict__ W,
                    void* __restrict__ Cv, int M, int N, int K){
  __shared__ __align__(16) u16 As[128 * 32];
  __shared__ __align__(16) u16 Bs[128 * 32];
  const int m0 = blockIdx.y * 128, n0 = blockIdx.x * 128;
  const int tid = threadIdx.x;
  const int wave = tid >> 6, lane = tid & 63;
  const int wm = wave >> 1, wn = wave & 1;
  const int g = lane >> 4, ln = lane & 15;
  const int r0 = tid >> 2;            // rows 0..63 (tid*16B == linear LDS dest)
  const int cc = (tid & 3) * 8;       // bf16 col within BK=32
  f32x4 acc[4][4] = {};
  const u16* xa0 = X + (size_t)(m0 + r0) * K + cc;
  const u16* xa1 = X + (size_t)(m0 + r0 + 64) * K + cc;
  const u16* wb0 = W + (size_t)(n0 + r0) * K + cc;
  const u16* wb1 = W + (size_t)(n0 + r0 + 64) * K + cc;

  for (int k0 = 0; k0 < K; k0 += 32){
    __syncthreads();                       // prior tile fully consumed
    gload_lds16(xa0 + k0, &As[tid * 8]);
    gload_lds16(xa1 + k0, &As[2048 + tid * 8]);
    gload_lds16(wb0 + k0, &Bs[tid * 8]);
    gload_lds16(wb1 + k0, &Bs[2048 + tid * 8]);
    __syncthreads();                       // barrier drains vmcnt
    bf16x8 a[4], b[4];
    #pragma unroll
    for (int f = 0; f < 4; f++) a[f] = *(const bf16x8*)&As[(wm * 64 + f * 16 + ln) * 32 + g * 8];
    #pragma unroll
    for (int f = 0; f < 4; f++) b[f] = *(const bf16x8*)&Bs[(wn * 64 + f * 16 + ln) * 32 + g * 8];
    #pragma unroll
    for (int i = 0; i < 4; i++)
      #pragma unroll
      for (int j = 0; j < 4; j++)
        acc[i][j] = __builtin_amdgcn_mfma_f32_16x16x32_bf16(a[i], b[j], acc[i][j], 0, 0, 0);
  }
  // epilogue: C/D layout col = lane&15, row = (lane>>4)*4 + reg  [m89]
  #pragma unroll
  for (int i = 0; i < 4; i++)
    #pragma unroll
    for (int j = 0; j < 4; j++)
      #pragma unroll
      for (int r = 0; r < 4; r++){
        int row = m0 + wm * 64 + i * 16 + g * 4 + r;
        int col = n0 + wn * 64 + j * 16 + ln;
        if (OUT_BF16) ((u16*)Cv)[(size_t)row * N + col] = f2bf(acc[i][j][r]);
        else          ((float*)Cv)[(size_t)row * N + col] = acc[i][j][r];
      }
}

// ---------------- partial RoPE (R=64), in place on packed QKV bf16 --------
__global__ void rope_kernel(u16* __restrict__ QKV,
                            const float* __restrict__ cosv, const float* __restrict__ sinv){
  int idx = blockIdx.x * 256 + threadIdx.x;
  if (idx >= S_LEN * (NH + NKVH) * 32) return;
  int dp   = idx & 31;
  int head = (idx >> 5) % (NH + NKVH);
  int s    = idx / ((NH + NKVH) * 32);
  u16* p = QKV + (size_t)s * QKVST + (head < NH ? head * HD : 4096 + (head - NH) * HD);
  float c  = cosv[s * 64 + dp];
  float sn = sinv[s * 64 + dp];  // cos/sin halves repeat: [dp] == [dp+32]
  float x0 = bf2f(p[dp]);
  float x1 = bf2f(p[dp + 32]);
  p[dp]      = f2bf(x0 * c - x1 * sn);
  p[dp + 32] = f2bf(x1 * c + x0 * sn);
}

// ---------------- V transpose: VT[kvh][vd][s] from packed QKV -------------
__global__ void vtrans_kernel(const u16* __restrict__ QKV, u16* __restrict__ VT){
  int idx = blockIdx.x * 256 + threadIdx.x;
  if (idx >= NKVH * HD * S_LEN) return;
  int s   = idx & (S_LEN - 1);
  int vd  = (idx >> 11) & (HD - 1);
  int kvh = idx >> 18;
  VT[idx] = QKV[(size_t)s * QKVST + 5120 + kvh * HD + vd];
}

// ---------------- causal flash attention with sink, GQA 4:1 ----------------
// 4 waves/block; block covers 64 q-rows of one head; KVBLK=64 staged in LDS.
// LDS tiles XOR-swizzled (col ^= (row&7)<<3) for conflict-free ds_read_b128.
__global__ __launch_bounds__(256, 4)
void attn_kernel(const u16* __restrict__ QKV, const u16* __restrict__ VT,
                 const float* __restrict__ sinkb, u16* __restrict__ AO){
  __shared__ __align__(16) u16 Ks[64 * 128];
  __shared__ __align__(16) u16 Vs[128 * 64];
  __shared__ __align__(16) u16 Ps[4][16 * 64];
  const int qt = gridDim.x - 1 - blockIdx.x;   // longest blocks first
  const int h = blockIdx.y;
  const int kvh = h >> 2;
  const int tid = threadIdx.x;
  const int w = tid >> 6, lane = tid & 63;
  const int g = lane >> 4, ln = lane & 15;
  const int q0 = qt * 64;
  const int qw = q0 + w * 16;

  // Q A-frags: row = ln (q), k = t*32 + g*8 + j
  bf16x8 qf[4];
  const u16* qrow = QKV + (size_t)(qw + ln) * QKVST + h * HD;
  #pragma unroll
  for (int t = 0; t < 4; t++) qf[t] = *(const bf16x8*)(qrow + t * 32 + g * 8);

  f32x4 O[8] = {};
  float m_r[4], l_r[4];
  #pragma unroll
  for (int r = 0; r < 4; r++){ m_r[r] = -3.0e38f; l_r[r] = 0.f; }

  const u16* Kbase = QKV + 4096 + kvh * HD;             // + row*QKVST
  const u16* Vbase = VT + (size_t)kvh * HD * S_LEN;     // + vd*S_LEN + k

  const int nkt = qt + 1;
  for (int kt = 0; kt < nkt; kt++){
    const int k0 = kt * 64;
    __syncthreads();                       // prior tile consumed by all waves
    // stage K tile [64 keys][128 d], source pre-swizzled so LDS dest is linear
    #pragma unroll
    for (int p = 0; p < 4; p++){
      int idx = p * 256 + tid;
      int r = idx >> 4, c16 = idx & 15;
      gload_lds16(Kbase + (size_t)(k0 + r) * QKVST + ((c16 ^ (r & 7)) * 8), &Ks[idx * 8]);
    }
    // stage V tile [128 vd][64 keys]
    #pragma unroll
    for (int p = 0; p < 4; p++){
      int idx = p * 256 + tid;
      int vd = idx >> 3, c8 = idx & 7;
      gload_lds16(Vbase + (size_t)vd * S_LEN + k0 + ((c8 ^ (vd & 7)) * 8), &Vs[idx * 8]);
    }
    __syncthreads();                       // drain vmcnt, tile visible

    // QK^T: 16 MFMAs -> sc[f], q row = g*4+r, key = k0 + f*16 + ln
    f32x4 sc[4] = {};
    #pragma unroll
    for (int f = 0; f < 4; f++){
      const int krow = f * 16 + ln;
      #pragma unroll
      for (int t = 0; t < 4; t++){
        bf16x8 kf = *(const bf16x8*)&Ks[krow * 128 + ((t * 32 + g * 8) ^ ((ln & 7) << 3))];
        sc[f] = __builtin_amdgcn_mfma_f32_16x16x32_bf16(qf[t], kf, sc[f], 0, 0, 0);
      }
    }
    // softmax update
    const bool diag = (kt == qt);
    float pv[4][4];
    #pragma unroll
    for (int f = 0; f < 4; f++)
      #pragma unroll
      for (int r = 0; r < 4; r++){
        float v = sc[f][r] * ATT_SCALE;
        if (diag && (k0 + f * 16 + ln > qw + g * 4 + r)) v = -1e30f;
        pv[f][r] = v;
      }
    float mn[4], sf_[4];
    #pragma unroll
    for (int r = 0; r < 4; r++){
      float mx = fmaxf(fmaxf(pv[0][r], pv[1][r]), fmaxf(pv[2][r], pv[3][r]));
      #pragma unroll
      for (int d = 1; d < 16; d <<= 1) mx = fmaxf(mx, __shfl_xor(mx, d));
      mn[r] = fmaxf(m_r[r], mx);
      sf_[r] = __expf(m_r[r] - mn[r]);
      m_r[r] = mn[r];
    }
    u16* Pw = Ps[w];
    #pragma unroll
    for (int r = 0; r < 4; r++){
      const int row = g * 4 + r;
      float rs = 0.f;
      #pragma unroll
      for (int f = 0; f < 4; f++){
        float p = __expf(pv[f][r] - mn[r]);
        rs += p;
        Pw[row * 64 + ((f * 16 + ln) ^ ((row & 7) << 3))] = f2bf(p);
      }
      #pragma unroll
      for (int d = 1; d < 16; d <<= 1) rs += __shfl_xor(rs, d);
      l_r[r] = l_r[r] * sf_[r] + rs;
    }
    #pragma unroll
    for (int fn = 0; fn < 8; fn++)
      #pragma unroll
      for (int r = 0; r < 4; r++) O[fn][r] *= sf_[r];

    // PV: P A-frag row = ln, k = kt2*32 + g*8 + j (wave-local LDS, no barrier)
    bf16x8 pa0 = *(const bf16x8*)&Pw[ln * 64 + ((g * 8)      ^ ((ln & 7) << 3))];
    bf16x8 pa1 = *(const bf16x8*)&Pw[ln * 64 + ((32 + g * 8) ^ ((ln & 7) << 3))];
    #pragma unroll
    for (int fn = 0; fn < 8; fn++){
      const int vr = fn * 16 + ln;
      bf16x8 v0 = *(const bf16x8*)&Vs[vr * 64 + ((g * 8)      ^ ((ln & 7) << 3))];
      bf16x8 v1 = *(const bf16x8*)&Vs[vr * 64 + ((32 + g * 8) ^ ((ln & 7) << 3))];
      O[fn] = __builtin_amdgcn_mfma_f32_16x16x32_bf16(pa0, v0, O[fn], 0, 0, 0);
      O[fn] = __builtin_amdgcn_mfma_f32_16x16x32_bf16(pa1, v1, O[fn], 0, 0, 0);
    }
  }
  // fold in sink: denominator += exp(sink - m_tot)
  float sb = sinkb[h];
  #pragma unroll
  for (int r = 0; r < 4; r++){
    float mt = fmaxf(m_r[r], sb);
    float lt = l_r[r] * __expf(m_r[r] - mt) + __expf(sb - mt);
    float osc = __expf(m_r[r] - mt) / lt;
    #pragma unroll
    for (int fn = 0; fn < 8; fn++)
      AO[(size_t)(qw + g * 4 + r) * AOST + h * HD + fn * 16 + ln] = f2bf(O[fn][r] * osc);
  }
}

// ---------------- host-side launch ----------------
extern "C" void kernel_launch(void* const* d_in, const int* in_sizes, int n_in,
                              void* d_out, int out_size, void* d_ws, size_t ws_size,
                              hipStream_t stream){
  (void)in_sizes; (void)n_in; (void)out_size; (void)ws_size;
  const float* hs    = (const float*)d_in[0];
  const float* cosv  = (const float*)d_in[1];
  const float* sinv  = (const float*)d_in[2];
  /* d_in[3] attention_mask: pure causal triu(NEG,1) - implemented directly */
  const float* Wq    = (const float*)d_in[4];
  const float* Wk    = (const float*)d_in[5];
  const float* Wv    = (const float*)d_in[6];
  const float* Wo    = (const float*)d_in[7];
  const float* sinkb = (const float*)d_in[8];
  float* out = (float*)d_out;

  char* ws = (char*)d_ws;
  u16* XB    = (u16*)(ws);                  //  8,388,608  X bf16 [2048][2048]
  u16* WQKVB = (u16*)(ws + 8388608);        // 25,165,824  Wqkv bf16 [6144][2048]
  u16* WOB   = (u16*)(ws + 33554432);       // 16,777,216  Wo bf16 [2048][4096]
  u16* QKV   = (u16*)(ws + 50331648);       // 25,165,824  QKV bf16 [2048][6144]
  u16* VT    = (u16*)(ws + 75497472);       //  4,194,304  V^T bf16 [8][128][2048]
  u16* AO    = (u16*)(ws + 79691776);       // 16,777,216  attn out bf16 [2048][4096]

  // converts (Wq/Wk/Wv packed into one [6144][2048] weight)
  cvt_kernel<<<4096, 256, 0, stream>>>((const f32x4*)hs, (u16x4*)XB, 1048576);
  cvt_kernel<<<8192, 256, 0, stream>>>((const f32x4*)Wq, (u16x4*)WQKVB, 2097152);
  cvt_kernel<<<2048, 256, 0, stream>>>((const f32x4*)Wk, (u16x4*)(WQKVB + 4096 * 2048), 524288);
  cvt_kernel<<<2048, 256, 0, stream>>>((const f32x4*)Wv, (u16x4*)(WQKVB + 5120 * 2048), 524288);
  cvt_kernel<<<8192, 256, 0, stream>>>((const f32x4*)Wo, (u16x4*)WOB, 2097152);

  // fused QKV projection: [2048][6144]
  gemm_bt_kernel<1><<<dim3(48, 16), 256, 0, stream>>>(XB, WQKVB, QKV, 2048, 6144, 2048);

  // RoPE (in place) + V transpose
  rope_kernel<<<10240, 256, 0, stream>>>(QKV, cosv, sinv);
  vtrans_kernel<<<8192, 256, 0, stream>>>(QKV, VT);

  // attention: grid (q-tiles of 64, heads)
  attn_kernel<<<dim3(32, 32), 256, 0, stream>>>(QKV, VT, sinkb, AO);

  // output projection (f32 out)
  gemm_bt_kernel<0><<<dim3(16, 16), 256, 0, stream>>>(AO, WOB, out, 2048, 2048, 4096);
}

// Round 3
// 269.576 us; speedup vs baseline: 2.2323x; 1.5656x over previous
//
#include <hip/hip_runtime.h>

typedef unsigned short u16;
typedef unsigned int   u32;
typedef __bf16  bf16x8 __attribute__((ext_vector_type(8)));
typedef float   f32x4  __attribute__((ext_vector_type(4)));
typedef u16     u16x4  __attribute__((ext_vector_type(4)));
typedef u16     u16x8  __attribute__((ext_vector_type(8)));

#define S_LEN 2048
#define NH 32
#define NKVH 8
#define HD 128
#define QKVST 6144          /* packed QKV row stride  */
#define AOST  4096          /* attn-out row stride    */
#define ATT_SCALE 0.08838834764831845f

__device__ __forceinline__ u16 f2bf(float f){
  u32 u = __builtin_bit_cast(u32, f);
  u += 0x7FFFu + ((u >> 16) & 1u);
  return (u16)(u >> 16);
}
__device__ __forceinline__ float bf2f(u16 h){
  u32 u = ((u32)h) << 16;
  return __builtin_bit_cast(float, u);
}
// async global->LDS, 16B per lane. Dest must be wave-uniform base + lane*16.
__device__ __forceinline__ void gload_lds16(const u16* g, u16* l){
  __builtin_amdgcn_global_load_lds(
      (const __attribute__((address_space(1))) void*)g,
      (__attribute__((address_space(3))) void*)l, 16, 0, 0);
}

// ---------------- f32 -> bf16 convert (vectorized) ----------------
__global__ void cvt_kernel(const f32x4* __restrict__ in, u16x4* __restrict__ out, int n4){
  int i = blockIdx.x * 256 + threadIdx.x;
  if (i >= n4) return;
  f32x4 v = in[i];
  u16x4 o;
  o[0] = f2bf(v[0]); o[1] = f2bf(v[1]); o[2] = f2bf(v[2]); o[3] = f2bf(v[3]);
  out[i] = o;
}

// ---------------- GEMM: C[M][N] = X[M][K] @ W[N][K]^T (bf16 in, f32 acc) ----
// 128x128 tile, BK=32, 4 waves (2x2), global_load_lds width-16 staging (m97).
template<int OUT_BF16>
__global__ __launch_bounds__(256, 2)
void gemm_bt_kernel(const u16* __restrict__ X, const u16* __restrict__ W,
                    void* __restrict__ Cv, int M, int N, int K){
  __shared__ __align__(16) u16 As[128 * 32];
  __shared__ __align__(16) u16 Bs[128 * 32];
  const int m0 = blockIdx.y * 128, n0 = blockIdx.x * 128;
  const int tid = threadIdx.x;
  const int wave = tid >> 6, lane = tid & 63;
  const int wm = wave >> 1, wn = wave & 1;
  const int g = lane >> 4, ln = lane & 15;
  const int r0 = tid >> 2;            // rows 0..63 (tid*16B == linear LDS dest)
  const int cc = (tid & 3) * 8;       // bf16 col within BK=32
  f32x4 acc[4][4] = {};
  const u16* xa0 = X + (size_t)(m0 + r0) * K + cc;
  const u16* xa1 = X + (size_t)(m0 + r0 + 64) * K + cc;
  const u16* wb0 = W + (size_t)(n0 + r0) * K + cc;
  const u16* wb1 = W + (size_t)(n0 + r0 + 64) * K + cc;

  for (int k0 = 0; k0 < K; k0 += 32){
    __syncthreads();                       // prior tile fully consumed
    gload_lds16(xa0 + k0, &As[tid * 8]);
    gload_lds16(xa1 + k0, &As[2048 + tid * 8]);
    gload_lds16(wb0 + k0, &Bs[tid * 8]);
    gload_lds16(wb1 + k0, &Bs[2048 + tid * 8]);
    __syncthreads();                       // barrier drains vmcnt
    bf16x8 a[4], b[4];
    #pragma unroll
    for (int f = 0; f < 4; f++) a[f] = *(const bf16x8*)&As[(wm * 64 + f * 16 + ln) * 32 + g * 8];
    #pragma unroll
    for (int f = 0; f < 4; f++) b[f] = *(const bf16x8*)&Bs[(wn * 64 + f * 16 + ln) * 32 + g * 8];
    #pragma unroll
    for (int i = 0; i < 4; i++)
      #pragma unroll
      for (int j = 0; j < 4; j++)
        acc[i][j] = __builtin_amdgcn_mfma_f32_16x16x32_bf16(a[i], b[j], acc[i][j], 0, 0, 0);
  }
  // epilogue: C/D layout col = lane&15, row = (lane>>4)*4 + reg  [m89]
  #pragma unroll
  for (int i = 0; i < 4; i++)
    #pragma unroll
    for (int j = 0; j < 4; j++)
      #pragma unroll
      for (int r = 0; r < 4; r++){
        int row = m0 + wm * 64 + i * 16 + g * 4 + r;
        int col = n0 + wn * 64 + j * 16 + ln;
        if (OUT_BF16) ((u16*)Cv)[(size_t)row * N + col] = f2bf(acc[i][j][r]);
        else          ((float*)Cv)[(size_t)row * N + col] = acc[i][j][r];
      }
}

// ---------------- partial RoPE (R=64), in place on packed QKV bf16 --------
__global__ void rope_kernel(u16* __restrict__ QKV,
                            const float* __restrict__ cosv, const float* __restrict__ sinv){
  int idx = blockIdx.x * 256 + threadIdx.x;
  if (idx >= S_LEN * (NH + NKVH) * 32) return;
  int dp   = idx & 31;
  int head = (idx >> 5) % (NH + NKVH);
  int s    = idx / ((NH + NKVH) * 32);
  u16* p = QKV + (size_t)s * QKVST + (head < NH ? head * HD : 4096 + (head - NH) * HD);
  float c  = cosv[s * 64 + dp];
  float sn = sinv[s * 64 + dp];  // cos/sin halves repeat: [dp] == [dp+32]
  float x0 = bf2f(p[dp]);
  float x1 = bf2f(p[dp + 32]);
  p[dp]      = f2bf(x0 * c - x1 * sn);
  p[dp + 32] = f2bf(x1 * c + x0 * sn);
}

// ---------------- V transpose: VT[kvh][vd][s] from packed QKV -------------
__global__ void vtrans_kernel(const u16* __restrict__ QKV, u16* __restrict__ VT){
  int idx = blockIdx.x * 256 + threadIdx.x;
  if (idx >= NKVH * HD * S_LEN) return;
  int s   = idx & (S_LEN - 1);
  int vd  = (idx >> 11) & (HD - 1);
  int kvh = idx >> 18;
  VT[idx] = QKV[(size_t)s * QKVST + 5120 + kvh * HD + vd];
}

// ---------------- causal flash attention with sink, GQA 4:1 ----------------
// 4 waves/block, 64 q-rows/block. KVBLK=64, double-buffered LDS prefetch
// (T3-minimum pipeline: stage(t+1) issued before compute(t), ONE barrier/tile).
// XCD-aware flat grid: b&7 == kvh so each XCD's K/V working set is 1MB (L2-fit).
__global__ __launch_bounds__(256, 2)
void attn_kernel(const u16* __restrict__ QKV, const u16* __restrict__ VT,
                 const float* __restrict__ sinkb, u16* __restrict__ AO){
  __shared__ __align__(16) u16 Ks[2][64 * 128];
  __shared__ __align__(16) u16 Vs[2][128 * 64];
  __shared__ __align__(16) u16 Ps[4][16 * 64];
  const int b   = blockIdx.x;
  const int kvh = b & 7;                 // XCD round-robin -> kvh per XCD
  const int h   = kvh * 4 + ((b >> 3) & 3);
  const int qt  = 31 - (b >> 5);         // longest blocks first
  const int tid = threadIdx.x;
  const int w = tid >> 6, lane = tid & 63;
  const int g = lane >> 4, ln = lane & 15;
  const int q0 = qt * 64;
  const int qw = q0 + w * 16;

  const u16* Kbase = QKV + 4096 + kvh * HD;             // + row*QKVST
  const u16* Vbase = VT + (size_t)kvh * HD * S_LEN;     // + vd*S_LEN + k

  // stage K/V tile kt into buffer buf (source pre-swizzled, LDS dest linear)
  auto stage = [&](int buf, int kt){
    const int k0 = kt * 64;
    #pragma unroll
    for (int p = 0; p < 4; p++){
      int idx = p * 256 + tid;
      int r = idx >> 4, c16 = idx & 15;
      gload_lds16(Kbase + (size_t)(k0 + r) * QKVST + ((c16 ^ (r & 7)) * 8), &Ks[buf][idx * 8]);
    }
    #pragma unroll
    for (int p = 0; p < 4; p++){
      int idx = p * 256 + tid;
      int vd = idx >> 3, c8 = idx & 7;
      gload_lds16(Vbase + (size_t)vd * S_LEN + k0 + ((c8 ^ (vd & 7)) * 8), &Vs[buf][idx * 8]);
    }
  };

  // Q A-frags: row = ln (q), k = t*32 + g*8 + j
  bf16x8 qf[4];
  const u16* qrow = QKV + (size_t)(qw + ln) * QKVST + h * HD;
  #pragma unroll
  for (int t = 0; t < 4; t++) qf[t] = *(const bf16x8*)(qrow + t * 32 + g * 8);

  f32x4 O[8] = {};
  float m_r[4], l_r[4];
  #pragma unroll
  for (int r = 0; r < 4; r++){ m_r[r] = -3.0e38f; l_r[r] = 0.f; }

  const int nkt = qt + 1;
  stage(0, 0);
  __syncthreads();                       // implicit vmcnt(0) drain: tile 0 ready
  int cur = 0;

  for (int kt = 0; kt < nkt; kt++){
    const int k0 = kt * 64;
    if (kt + 1 < nkt) stage(cur ^ 1, kt + 1);   // prefetch overlaps compute

    // QK^T: 16 MFMAs -> sc[f], q row = g*4+r, key = k0 + f*16 + ln
    const u16* Kc = Ks[cur];
    f32x4 sc[4] = {};
    __builtin_amdgcn_s_setprio(1);
    #pragma unroll
    for (int f = 0; f < 4; f++){
      const int krow = f * 16 + ln;
      #pragma unroll
      for (int t = 0; t < 4; t++){
        bf16x8 kf = *(const bf16x8*)&Kc[krow * 128 + ((t * 32 + g * 8) ^ ((ln & 7) << 3))];
        sc[f] = __builtin_amdgcn_mfma_f32_16x16x32_bf16(qf[t], kf, sc[f], 0, 0, 0);
      }
    }
    __builtin_amdgcn_s_setprio(0);

    // softmax update
    const bool diag = (kt == qt);
    float pv[4][4];
    #pragma unroll
    for (int f = 0; f < 4; f++)
      #pragma unroll
      for (int r = 0; r < 4; r++){
        float v = sc[f][r] * ATT_SCALE;
        if (diag && (k0 + f * 16 + ln > qw + g * 4 + r)) v = -1e30f;
        pv[f][r] = v;
      }
    float mn[4], sf_[4];
    #pragma unroll
    for (int r = 0; r < 4; r++){
      float mx = fmaxf(fmaxf(pv[0][r], pv[1][r]), fmaxf(pv[2][r], pv[3][r]));
      #pragma unroll
      for (int d = 1; d < 16; d <<= 1) mx = fmaxf(mx, __shfl_xor(mx, d));
      mn[r] = fmaxf(m_r[r], mx);
      sf_[r] = __expf(m_r[r] - mn[r]);
      m_r[r] = mn[r];
    }
    u16* Pw = Ps[w];
    #pragma unroll
    for (int r = 0; r < 4; r++){
      const int row = g * 4 + r;
      float rs = 0.f;
      #pragma unroll
      for (int f = 0; f < 4; f++){
        float p = __expf(pv[f][r] - mn[r]);
        rs += p;
        Pw[row * 64 + ((f * 16 + ln) ^ ((row & 7) << 3))] = f2bf(p);
      }
      #pragma unroll
      for (int d = 1; d < 16; d <<= 1) rs += __shfl_xor(rs, d);
      l_r[r] = l_r[r] * sf_[r] + rs;
    }
    #pragma unroll
    for (int fn = 0; fn < 8; fn++)
      #pragma unroll
      for (int r = 0; r < 4; r++) O[fn][r] *= sf_[r];

    // PV: P A-frag row = ln, k = kk*32 + g*8 + j (wave-local LDS)
    const u16* Vc = Vs[cur];
    bf16x8 pa0 = *(const bf16x8*)&Pw[ln * 64 + ((g * 8)      ^ ((ln & 7) << 3))];
    bf16x8 pa1 = *(const bf16x8*)&Pw[ln * 64 + ((32 + g * 8) ^ ((ln & 7) << 3))];
    __builtin_amdgcn_s_setprio(1);
    #pragma unroll
    for (int fn = 0; fn < 8; fn++){
      const int vr = fn * 16 + ln;
      bf16x8 v0 = *(const bf16x8*)&Vc[vr * 64 + ((g * 8)      ^ ((ln & 7) << 3))];
      bf16x8 v1 = *(const bf16x8*)&Vc[vr * 64 + ((32 + g * 8) ^ ((ln & 7) << 3))];
      O[fn] = __builtin_amdgcn_mfma_f32_16x16x32_bf16(pa0, v0, O[fn], 0, 0, 0);
      O[fn] = __builtin_amdgcn_mfma_f32_16x16x32_bf16(pa1, v1, O[fn], 0, 0, 0);
    }
    __builtin_amdgcn_s_setprio(0);

    __syncthreads();   // ONE barrier/tile: drains prefetch vmcnt + guards reuse
    cur ^= 1;
  }
  // fold in sink: denominator += exp(sink - m_tot)
  float sb = sinkb[h];
  #pragma unroll
  for (int r = 0; r < 4; r++){
    float mt = fmaxf(m_r[r], sb);
    float lt = l_r[r] * __expf(m_r[r] - mt) + __expf(sb - mt);
    float osc = __expf(m_r[r] - mt) / lt;
    #pragma unroll
    for (int fn = 0; fn < 8; fn++)
      AO[(size_t)(qw + g * 4 + r) * AOST + h * HD + fn * 16 + ln] = f2bf(O[fn][r] * osc);
  }
}

// ---------------- host-side launch ----------------
extern "C" void kernel_launch(void* const* d_in, const int* in_sizes, int n_in,
                              void* d_out, int out_size, void* d_ws, size_t ws_size,
                              hipStream_t stream){
  (void)in_sizes; (void)n_in; (void)out_size; (void)ws_size;
  const float* hs    = (const float*)d_in[0];
  const float* cosv  = (const float*)d_in[1];
  const float* sinv  = (const float*)d_in[2];
  /* d_in[3] attention_mask: pure causal triu(NEG,1) - implemented directly */
  const float* Wq    = (const float*)d_in[4];
  const float* Wk    = (const float*)d_in[5];
  const float* Wv    = (const float*)d_in[6];
  const float* Wo    = (const float*)d_in[7];
  const float* sinkb = (const float*)d_in[8];
  float* out = (float*)d_out;

  char* ws = (char*)d_ws;
  u16* XB    = (u16*)(ws);                  //  8,388,608  X bf16 [2048][2048]
  u16* WQKVB = (u16*)(ws + 8388608);        // 25,165,824  Wqkv bf16 [6144][2048]
  u16* WOB   = (u16*)(ws + 33554432);       // 16,777,216  Wo bf16 [2048][4096]
  u16* QKV   = (u16*)(ws + 50331648);       // 25,165,824  QKV bf16 [2048][6144]
  u16* VT    = (u16*)(ws + 75497472);       //  4,194,304  V^T bf16 [8][128][2048]
  u16* AO    = (u16*)(ws + 79691776);       // 16,777,216  attn out bf16 [2048][4096]

  // converts (Wq/Wk/Wv packed into one [6144][2048] weight)
  cvt_kernel<<<4096, 256, 0, stream>>>((const f32x4*)hs, (u16x4*)XB, 1048576);
  cvt_kernel<<<8192, 256, 0, stream>>>((const f32x4*)Wq, (u16x4*)WQKVB, 2097152);
  cvt_kernel<<<2048, 256, 0, stream>>>((const f32x4*)Wk, (u16x4*)(WQKVB + 4096 * 2048), 524288);
  cvt_kernel<<<2048, 256, 0, stream>>>((const f32x4*)Wv, (u16x4*)(WQKVB + 5120 * 2048), 524288);
  cvt_kernel<<<8192, 256, 0, stream>>>((const f32x4*)Wo, (u16x4*)WOB, 2097152);

  // fused QKV projection: [2048][6144]
  gemm_bt_kernel<1><<<dim3(48, 16), 256, 0, stream>>>(XB, WQKVB, QKV, 2048, 6144, 2048);

  // RoPE (in place) + V transpose
  rope_kernel<<<10240, 256, 0, stream>>>(QKV, cosv, sinv);
  vtrans_kernel<<<8192, 256, 0, stream>>>(QKV, VT);

  // attention: flat 1024-block grid, XCD-aligned kvh
  attn_kernel<<<dim3(1024), 256, 0, stream>>>(QKV, VT, sinkb, AO);

  // output projection (f32 out)
  gemm_bt_kernel<0><<<dim3(16, 16), 256, 0, stream>>>(AO, WOB, out, 2048, 2048, 4096);
}

// Round 4
// 259.264 us; speedup vs baseline: 2.3211x; 1.0398x over previous
//
#include <hip/hip_runtime.h>

typedef unsigned short u16;
typedef unsigned int   u32;
typedef __bf16  bf16x8 __attribute__((ext_vector_type(8)));
typedef float   f32x4  __attribute__((ext_vector_type(4)));
typedef u16     u16x4  __attribute__((ext_vector_type(4)));
typedef u16     u16x8  __attribute__((ext_vector_type(8)));

#define S_LEN 2048
#define NH 32
#define NKVH 8
#define HD 128
#define QKVST 6144          /* packed QKV row stride  */
#define AOST  4096          /* attn-out row stride    */
#define ATT_SCALE 0.08838834764831845f
#define RESCALE_THR 8.0f

__device__ __forceinline__ u16 f2bf(float f){
  u32 u = __builtin_bit_cast(u32, f);
  u += 0x7FFFu + ((u >> 16) & 1u);
  return (u16)(u >> 16);
}
__device__ __forceinline__ float bf2f(u16 h){
  u32 u = ((u32)h) << 16;
  return __builtin_bit_cast(float, u);
}
// async global->LDS, 16B per lane. Dest must be wave-uniform base + lane*16.
__device__ __forceinline__ void gload_lds16(const u16* g, u16* l){
  __builtin_amdgcn_global_load_lds(
      (const __attribute__((address_space(1))) void*)g,
      (__attribute__((address_space(3))) void*)l, 16, 0, 0);
}

// ---------------- f32 -> bf16 convert (vectorized) ----------------
__global__ void cvt_kernel(const f32x4* __restrict__ in, u16x4* __restrict__ out, int n4){
  int i = blockIdx.x * 256 + threadIdx.x;
  if (i >= n4) return;
  f32x4 v = in[i];
  u16x4 o;
  o[0] = f2bf(v[0]); o[1] = f2bf(v[1]); o[2] = f2bf(v[2]); o[3] = f2bf(v[3]);
  out[i] = o;
}

// ---------------- GEMM: C[M][N] = X[M][K] @ W[N][K]^T (bf16 in, f32 acc) ----
// 128x128 tile, BK=64 (2x [128][32] sub-tiles), double-buffered prefetch
// pipeline (stage t+1 before compute t, ONE barrier per K-tile). ROPE=1 fuses
// partial RoPE (pairs = acc fragments j, j+2; wn==0 <=> in-head d<64).
template<int OUT_BF16, int ROPE>
__global__ __launch_bounds__(256, 2)
void gemm_bt_kernel(const u16* __restrict__ X, const u16* __restrict__ W,
                    void* __restrict__ Cv, int M, int N, int K,
                    const float* __restrict__ cosv, const float* __restrict__ sinv){
  __shared__ __align__(16) u16 As[2][2][128 * 32];
  __shared__ __align__(16) u16 Bs[2][2][128 * 32];
  const int m0 = blockIdx.y * 128, n0 = blockIdx.x * 128;
  const int tid = threadIdx.x;
  const int wave = tid >> 6, lane = tid & 63;
  const int wm = wave >> 1, wn = wave & 1;
  const int g = lane >> 4, ln = lane & 15;
  const int r0 = tid >> 2;            // rows 0..63 (tid*16B == linear LDS dest)
  const int cc = (tid & 3) * 8;       // bf16 col within sub-tile BK=32
  f32x4 acc[4][4] = {};
  const u16* xa0 = X + (size_t)(m0 + r0) * K + cc;
  const u16* xa1 = X + (size_t)(m0 + r0 + 64) * K + cc;
  const u16* wb0 = W + (size_t)(n0 + r0) * K + cc;
  const u16* wb1 = W + (size_t)(n0 + r0 + 64) * K + cc;

  auto stage = [&](int buf, int k0){
    #pragma unroll
    for (int s = 0; s < 2; s++){
      const int kc = k0 + s * 32;
      gload_lds16(xa0 + kc, &As[buf][s][tid * 8]);
      gload_lds16(xa1 + kc, &As[buf][s][2048 + tid * 8]);
      gload_lds16(wb0 + kc, &Bs[buf][s][tid * 8]);
      gload_lds16(wb1 + kc, &Bs[buf][s][2048 + tid * 8]);
    }
  };

  stage(0, 0);
  __syncthreads();                       // implicit vmcnt(0): tile 0 ready
  int cur = 0;
  for (int k0 = 0; k0 < K; k0 += 64){
    if (k0 + 64 < K) stage(cur ^ 1, k0 + 64);   // prefetch overlaps compute
    #pragma unroll
    for (int s = 0; s < 2; s++){
      bf16x8 a[4], b[4];
      #pragma unroll
      for (int f = 0; f < 4; f++) a[f] = *(const bf16x8*)&As[cur][s][(wm * 64 + f * 16 + ln) * 32 + g * 8];
      #pragma unroll
      for (int f = 0; f < 4; f++) b[f] = *(const bf16x8*)&Bs[cur][s][(wn * 64 + f * 16 + ln) * 32 + g * 8];
      __builtin_amdgcn_s_setprio(1);
      #pragma unroll
      for (int i = 0; i < 4; i++)
        #pragma unroll
        for (int j = 0; j < 4; j++)
          acc[i][j] = __builtin_amdgcn_mfma_f32_16x16x32_bf16(a[i], b[j], acc[i][j], 0, 0, 0);
      __builtin_amdgcn_s_setprio(0);
    }
    __syncthreads();   // ONE barrier/tile: drains prefetch vmcnt + guards reuse
    cur ^= 1;
  }
  // fused partial RoPE: Q/K column blocks (n0<5120), first-half dims (wn==0)
  if (ROPE && wn == 0 && n0 < 5120){
    #pragma unroll
    for (int i = 0; i < 4; i++)
      #pragma unroll
      for (int r = 0; r < 4; r++){
        const int row = m0 + wm * 64 + i * 16 + g * 4 + r;
        #pragma unroll
        for (int j = 0; j < 2; j++){
          const int d = j * 16 + ln;               // 0..31, partner d+32
          float c  = cosv[row * 64 + d];
          float sn = sinv[row * 64 + d];
          float x0 = acc[i][j][r], x1 = acc[i][j + 2][r];
          acc[i][j][r]     = x0 * c - x1 * sn;
          acc[i][j + 2][r] = x1 * c + x0 * sn;
        }
      }
  }
  // epilogue: C/D layout col = lane&15, row = (lane>>4)*4 + reg  [m89]
  #pragma unroll
  for (int i = 0; i < 4; i++)
    #pragma unroll
    for (int j = 0; j < 4; j++)
      #pragma unroll
      for (int r = 0; r < 4; r++){
        int row = m0 + wm * 64 + i * 16 + g * 4 + r;
        int col = n0 + wn * 64 + j * 16 + ln;
        if (OUT_BF16) ((u16*)Cv)[(size_t)row * N + col] = f2bf(acc[i][j][r]);
        else          ((float*)Cv)[(size_t)row * N + col] = acc[i][j][r];
      }
}

// ---------------- V transpose: VT[kvh][vd][s] from packed QKV -------------
__global__ void vtrans_kernel(const u16* __restrict__ QKV, u16* __restrict__ VT){
  int idx = blockIdx.x * 256 + threadIdx.x;
  if (idx >= NKVH * HD * S_LEN) return;
  int s   = idx & (S_LEN - 1);
  int vd  = (idx >> 11) & (HD - 1);
  int kvh = idx >> 18;
  VT[idx] = QKV[(size_t)s * QKVST + 5120 + kvh * HD + vd];
}

// ---------------- causal flash attention with sink, GQA 4:1 ----------------
// 4 waves/block, 64 q-rows/block, KVBLK=64, double-buffered LDS prefetch.
// V tile augmented with a ones-row (rows 128..143): 9th PV fragment
// accumulates l = sum(exp) via MFMA (no per-tile sum-reduce). Defer-max
// rescale (T13, THR=8). XCD-aware flat grid: b&7 == kvh.
__global__ __launch_bounds__(256, 2)
void attn_kernel(const u16* __restrict__ QKV, const u16* __restrict__ VT,
                 const float* __restrict__ sinkb, u16* __restrict__ AO){
  __shared__ __align__(16) u16 Ks[2][64 * 128];
  __shared__ __align__(16) u16 Vs[2][144 * 64];
  __shared__ __align__(16) u16 Ps[4][16 * 64];
  const int b   = blockIdx.x;
  const int kvh = b & 7;                 // XCD round-robin -> kvh per XCD
  const int h   = kvh * 4 + ((b >> 3) & 3);
  const int qt  = 31 - (b >> 5);         // longest blocks first
  const int tid = threadIdx.x;
  const int w = tid >> 6, lane = tid & 63;
  const int g = lane >> 4, ln = lane & 15;
  const int q0 = qt * 64;
  const int qw = q0 + w * 16;

  const u16* Kbase = QKV + 4096 + kvh * HD;             // + row*QKVST
  const u16* Vbase = VT + (size_t)kvh * HD * S_LEN;     // + vd*S_LEN + k

  auto stage = [&](int buf, int kt){
    const int k0 = kt * 64;
    #pragma unroll
    for (int p = 0; p < 4; p++){
      int idx = p * 256 + tid;
      int r = idx >> 4, c16 = idx & 15;
      gload_lds16(Kbase + (size_t)(k0 + r) * QKVST + ((c16 ^ (r & 7)) * 8), &Ks[buf][idx * 8]);
    }
    #pragma unroll
    for (int p = 0; p < 4; p++){
      int idx = p * 256 + tid;
      int vd = idx >> 3, c8 = idx & 7;
      gload_lds16(Vbase + (size_t)vd * S_LEN + k0 + ((c8 ^ (vd & 7)) * 8), &Vs[buf][idx * 8]);
    }
  };

  // ones-rows for l-accumulation: row 128 = 1.0, rows 129..143 = 0
  for (int i = tid; i < 16 * 64; i += 256){
    u16 v = (i < 64) ? (u16)0x3F80 : (u16)0;
    Vs[0][128 * 64 + i] = v;
    Vs[1][128 * 64 + i] = v;
  }

  // Q A-frags: row = ln (q), k = t*32 + g*8 + j
  bf16x8 qf[4];
  const u16* qrow = QKV + (size_t)(qw + ln) * QKVST + h * HD;
  #pragma unroll
  for (int t = 0; t < 4; t++) qf[t] = *(const bf16x8*)(qrow + t * 32 + g * 8);

  f32x4 O[9] = {};                       // O[8] = l accumulator (col ln==0)
  float m_r[4];
  #pragma unroll
  for (int r = 0; r < 4; r++) m_r[r] = -3.0e38f;

  const int nkt = qt + 1;
  stage(0, 0);
  __syncthreads();
  int cur = 0;

  for (int kt = 0; kt < nkt; kt++){
    const int k0 = kt * 64;
    if (kt + 1 < nkt) stage(cur ^ 1, kt + 1);   // prefetch overlaps compute

    // QK^T: 16 MFMAs -> sc[f], q row = g*4+r, key = k0 + f*16 + ln
    const u16* Kc = Ks[cur];
    f32x4 sc[4] = {};
    __builtin_amdgcn_s_setprio(1);
    #pragma unroll
    for (int f = 0; f < 4; f++){
      const int krow = f * 16 + ln;
      #pragma unroll
      for (int t = 0; t < 4; t++){
        bf16x8 kf = *(const bf16x8*)&Kc[krow * 128 + ((t * 32 + g * 8) ^ ((ln & 7) << 3))];
        sc[f] = __builtin_amdgcn_mfma_f32_16x16x32_bf16(qf[t], kf, sc[f], 0, 0, 0);
      }
    }
    __builtin_amdgcn_s_setprio(0);

    const bool diag = (kt == qt);
    float pv[4][4];
    #pragma unroll
    for (int f = 0; f < 4; f++)
      #pragma unroll
      for (int r = 0; r < 4; r++){
        float v = sc[f][r] * ATT_SCALE;
        if (diag && (k0 + f * 16 + ln > qw + g * 4 + r)) v = -1e30f;
        pv[f][r] = v;
      }
    // per-row tile max (in-lane tree + 4-step shuffle over the 16-lane group)
    float mx[4];
    #pragma unroll
    for (int r = 0; r < 4; r++){
      float t = fmaxf(fmaxf(pv[0][r], pv[1][r]), fmaxf(pv[2][r], pv[3][r]));
      #pragma unroll
      for (int d = 1; d < 16; d <<= 1) t = fmaxf(t, __shfl_xor(t, d));
      mx[r] = t;
    }
    // defer-max: only rescale when some row grew past THR
    int ok = (mx[0] <= m_r[0] + RESCALE_THR) & (mx[1] <= m_r[1] + RESCALE_THR)
           & (mx[2] <= m_r[2] + RESCALE_THR) & (mx[3] <= m_r[3] + RESCALE_THR);
    if (!__all(ok)){
      float sf_[4];
      #pragma unroll
      for (int r = 0; r < 4; r++){
        float mn = fmaxf(m_r[r], mx[r]);
        sf_[r] = __expf(m_r[r] - mn);
        m_r[r] = mn;
      }
      #pragma unroll
      for (int fn = 0; fn < 9; fn++)
        #pragma unroll
        for (int r = 0; r < 4; r++) O[fn][r] *= sf_[r];
    }
    // P = exp(s - m), store bf16 (swizzled) for PV A-frag
    u16* Pw = Ps[w];
    #pragma unroll
    for (int r = 0; r < 4; r++){
      const int row = g * 4 + r;
      #pragma unroll
      for (int f = 0; f < 4; f++){
        float p = __expf(pv[f][r] - m_r[r]);
        Pw[row * 64 + ((f * 16 + ln) ^ ((row & 7) << 3))] = f2bf(p);
      }
    }
    // PV (9 fragments; fn=8 hits the ones-row -> l): wave-local LDS
    const u16* Vc = Vs[cur];
    bf16x8 pa0 = *(const bf16x8*)&Pw[ln * 64 + ((g * 8)      ^ ((ln & 7) << 3))];
    bf16x8 pa1 = *(const bf16x8*)&Pw[ln * 64 + ((32 + g * 8) ^ ((ln & 7) << 3))];
    __builtin_amdgcn_s_setprio(1);
    #pragma unroll
    for (int fn = 0; fn < 9; fn++){
      const int vr = fn * 16 + ln;
      bf16x8 v0 = *(const bf16x8*)&Vc[vr * 64 + ((g * 8)      ^ ((ln & 7) << 3))];
      bf16x8 v1 = *(const bf16x8*)&Vc[vr * 64 + ((32 + g * 8) ^ ((ln & 7) << 3))];
      O[fn] = __builtin_amdgcn_mfma_f32_16x16x32_bf16(pa0, v0, O[fn], 0, 0, 0);
      O[fn] = __builtin_amdgcn_mfma_f32_16x16x32_bf16(pa1, v1, O[fn], 0, 0, 0);
    }
    __builtin_amdgcn_s_setprio(0);

    __syncthreads();   // ONE barrier/tile: drains prefetch vmcnt + guards reuse
    cur ^= 1;
  }
  // l lives in O[8][r] of lanes with ln==0; broadcast within 16-lane group,
  // then fold sink into the denominator
  float sb = sinkb[h];
  #pragma unroll
  for (int r = 0; r < 4; r++){
    float l = __shfl(O[8][r], lane & 48);
    float mt = fmaxf(m_r[r], sb);
    float lt = l * __expf(m_r[r] - mt) + __expf(sb - mt);
    float osc = __expf(m_r[r] - mt) / lt;
    #pragma unroll
    for (int fn = 0; fn < 8; fn++)
      AO[(size_t)(qw + g * 4 + r) * AOST + h * HD + fn * 16 + ln] = f2bf(O[fn][r] * osc);
  }
}

// ---------------- host-side launch ----------------
extern "C" void kernel_launch(void* const* d_in, const int* in_sizes, int n_in,
                              void* d_out, int out_size, void* d_ws, size_t ws_size,
                              hipStream_t stream){
  (void)in_sizes; (void)n_in; (void)out_size; (void)ws_size;
  const float* hs    = (const float*)d_in[0];
  const float* cosv  = (const float*)d_in[1];
  const float* sinv  = (const float*)d_in[2];
  /* d_in[3] attention_mask: pure causal triu(NEG,1) - implemented directly */
  const float* Wq    = (const float*)d_in[4];
  const float* Wk    = (const float*)d_in[5];
  const float* Wv    = (const float*)d_in[6];
  const float* Wo    = (const float*)d_in[7];
  const float* sinkb = (const float*)d_in[8];
  float* out = (float*)d_out;

  char* ws = (char*)d_ws;
  u16* XB    = (u16*)(ws);                  //  8,388,608  X bf16 [2048][2048]
  u16* WQKVB = (u16*)(ws + 8388608);        // 25,165,824  Wqkv bf16 [6144][2048]
  u16* WOB   = (u16*)(ws + 33554432);       // 16,777,216  Wo bf16 [2048][4096]
  u16* QKV   = (u16*)(ws + 50331648);       // 25,165,824  QKV bf16 [2048][6144]
  u16* VT    = (u16*)(ws + 75497472);       //  4,194,304  V^T bf16 [8][128][2048]
  u16* AO    = (u16*)(ws + 79691776);       // 16,777,216  attn out bf16 [2048][4096]

  // converts (Wq/Wk/Wv packed into one [6144][2048] weight)
  cvt_kernel<<<4096, 256, 0, stream>>>((const f32x4*)hs, (u16x4*)XB, 1048576);
  cvt_kernel<<<8192, 256, 0, stream>>>((const f32x4*)Wq, (u16x4*)WQKVB, 2097152);
  cvt_kernel<<<2048, 256, 0, stream>>>((const f32x4*)Wk, (u16x4*)(WQKVB + 4096 * 2048), 524288);
  cvt_kernel<<<2048, 256, 0, stream>>>((const f32x4*)Wv, (u16x4*)(WQKVB + 5120 * 2048), 524288);
  cvt_kernel<<<8192, 256, 0, stream>>>((const f32x4*)Wo, (u16x4*)WOB, 2097152);

  // fused QKV projection + RoPE epilogue: [2048][6144]
  gemm_bt_kernel<1, 1><<<dim3(48, 16), 256, 0, stream>>>(XB, WQKVB, QKV, 2048, 6144, 2048, cosv, sinv);

  // V transpose (V region carries no rope)
  vtrans_kernel<<<8192, 256, 0, stream>>>(QKV, VT);

  // attention: flat 1024-block grid, XCD-aligned kvh
  attn_kernel<<<dim3(1024), 256, 0, stream>>>(QKV, VT, sinkb, AO);

  // output projection (f32 out)
  gemm_bt_kernel<0, 0><<<dim3(16, 16), 256, 0, stream>>>(AO, WOB, out, 2048, 2048, 4096, nullptr, nullptr);
}